// Round 10
// baseline (502.980 us; speedup 1.0000x reference)
//
#include <hip/hip_runtime.h>
#include <hip/hip_fp16.h>
#include <math.h>

// ---------------------------------------------------------------------------
// RecurrentGCN: 2x GConvLSTM(Cheb K=5) + ReLU + collapsed 4-linear head.
// R10 changes:
//  - k_prop16 v2: lane = (node, feature-quad), 8 nodes/wave, serial edge walk
//    with 4 unrolled gather chains. ZERO shfl/LDS (R9 post-mortem: the
//    32-ds_bpermute reduce tail was ~1/3 of prop time). Coalesced stores.
//  - k_gates v3: weights staged in LDS (two k-halves, 60.7KB total). Inner
//    loop reads are wave-uniform ds_read_b128 broadcasts -> no SGPR wall
//    (R5/R9) and no VGPR-starved vmcnt (R8).
//  - k_deg + k_cnt merged into k_degcnt.
// ---------------------------------------------------------------------------

#define TPB 256
#define PADM 15    // segment pad: round up to multiple of 16
#define BW 128     // nodes per bucket
#define NB 391     // ceil(50000/128)
#define CAP 6016   // per-bucket arena capacity
#define EPB 8192   // edges per k_bucket block

// ---- bucketing: one read pass, both src- and dst-bucketed arenas ----------
__global__ __launch_bounds__(512) void k_bucket(
    const int* __restrict__ ei, const float* __restrict__ ew,
    int* __restrict__ dcnt, int* __restrict__ scnt, uint2* __restrict__ arD,
    uint2* __restrict__ arS, int E) {
  __shared__ int hd[NB], hs[NB];
  __shared__ int cd[NB], cs[NB];
  int tid = threadIdx.x;
  int base = blockIdx.x * EPB;
  int end = min(base + EPB, E);
  for (int j = tid; j < NB; j += 512) {
    hd[j] = 0;
    hs[j] = 0;
  }
  __syncthreads();
  for (int i = base + tid; i < end; i += 512) {
    int s = ei[i], d = ei[E + i];
    atomicAdd(&hs[s >> 7], 1);
    atomicAdd(&hd[d >> 7], 1);
  }
  __syncthreads();
  for (int j = tid; j < NB; j += 512) {
    cd[j] = (hd[j] > 0) ? atomicAdd(&dcnt[j], hd[j]) : 0;
    cs[j] = (hs[j] > 0) ? atomicAdd(&scnt[j], hs[j]) : 0;
  }
  __syncthreads();
  for (int i = base + tid; i < end; i += 512) {
    int s = ei[i], d = ei[E + i];
    unsigned wbits = __float_as_uint(ew[i]);
    int bs = s >> 7, bd = d >> 7;
    int ps = atomicAdd(&cs[bs], 1);
    int pd = atomicAdd(&cd[bd], 1);
    if (ps < CAP) arS[(size_t)bs * CAP + ps] = make_uint2((unsigned)s, wbits);
    if (pd < CAP)
      arD[(size_t)bd * CAP + pd] =
          make_uint2((unsigned)s | ((unsigned)(d & 127) << 16), wbits);
  }
}

// ---- per-bucket degree (arS) + in-degree counts (arD), merged -------------
__global__ __launch_bounds__(TPB) void k_degcnt(
    const uint2* __restrict__ arS, const int* __restrict__ scnt,
    const uint2* __restrict__ arD, const int* __restrict__ dcnt,
    float* __restrict__ dinv, int* __restrict__ cnt, int N) {
  __shared__ float dacc[BW];
  __shared__ int c[BW];
  int b = blockIdx.x, tid = threadIdx.x;
  if (tid < BW) {
    dacc[tid] = 0.f;
    c[tid] = 0;
  }
  __syncthreads();
  int nbs = scnt[b];
  const uint2* ps = arS + (size_t)b * CAP;
  for (int i = tid; i < nbs; i += TPB) {
    uint2 e = ps[i];
    atomicAdd(&dacc[e.x & 127], __uint_as_float(e.y));
  }
  int nbd = dcnt[b];
  const uint2* pd = arD + (size_t)b * CAP;
  for (int i = tid; i < nbd; i += TPB) {
    atomicAdd(&c[(pd[i].x >> 16) & 127], 1);
  }
  __syncthreads();
  int node = b * BW + tid;
  if (tid < BW && node < N) {
    float dg = dacc[tid];
    dinv[node] = (dg > 0.f) ? 1.0f / sqrtf(fmaxf(dg, 1e-12f)) : 0.f;
    cnt[node] = c[tid];
  }
}

// ---- 3-kernel exclusive scan of padded counts -----------------------------
__global__ __launch_bounds__(TPB) void k_scan1(
    const int* __restrict__ cnt, int* __restrict__ excl, int* __restrict__ bsum,
    int n) {
  __shared__ int sh[TPB];
  int tid = threadIdx.x;
  int i = blockIdx.x * TPB + tid;
  int v = (i < n) ? ((cnt[i] + PADM) & ~PADM) : 0;
  sh[tid] = v;
  __syncthreads();
  for (int off = 1; off < TPB; off <<= 1) {
    int t = (tid >= off) ? sh[tid - off] : 0;
    __syncthreads();
    sh[tid] += t;
    __syncthreads();
  }
  if (i < n) excl[i] = sh[tid] - v;
  if (tid == TPB - 1) bsum[blockIdx.x] = sh[TPB - 1];
}

__global__ __launch_bounds__(TPB) void k_scan2(int* __restrict__ bsum, int nb) {
  __shared__ int sh[TPB];
  int tid = threadIdx.x;
  int v = (tid < nb) ? bsum[tid] : 0;
  sh[tid] = v;
  __syncthreads();
  for (int off = 1; off < TPB; off <<= 1) {
    int t = (tid >= off) ? sh[tid - off] : 0;
    __syncthreads();
    sh[tid] += t;
    __syncthreads();
  }
  if (tid < nb) bsum[tid] = sh[tid] - v;
}

__global__ __launch_bounds__(TPB) void k_scan3(
    const int* __restrict__ excl, const int* __restrict__ bsum,
    const int* __restrict__ cnt, int* __restrict__ rp, int n) {
  int i = blockIdx.x * TPB + threadIdx.x;
  if (i < n) {
    int r = excl[i] + bsum[i >> 8];
    rp[i] = r;
    if (i == n - 1) rp[n] = r + ((cnt[i] + PADM) & ~PADM);
  }
}

// ---- final CSR scatter: LDS cursors + fused norm --------------------------
__global__ __launch_bounds__(TPB) void k_csr(
    const uint2* __restrict__ arD, const int* __restrict__ dcnt,
    const int* __restrict__ rp, const float* __restrict__ dinv,
    uint2* __restrict__ epk, int N) {
  __shared__ int cur[BW];
  __shared__ float dloc[BW];
  int b = blockIdx.x, tid = threadIdx.x;
  int node = b * BW + tid;
  if (tid < BW) {
    cur[tid] = (node < N) ? rp[node] : 0;
    dloc[tid] = (node < N) ? dinv[node] : 0.f;
  }
  __syncthreads();
  int nb = dcnt[b];
  const uint2* p = arD + (size_t)b * CAP;
  for (int i = tid; i < nb; i += TPB) {
    uint2 e = p[i];
    int src = e.x & 0xFFFF;
    int dl = (e.x >> 16) & 127;
    float nv = -dinv[src] * __uint_as_float(e.y) * dloc[dl];
    int pos = atomicAdd(&cur[dl], 1);
    epk[pos] = make_uint2((unsigned)src, __float_as_uint(nv));
  }
}

// ---- f32 -> fp16 table build ----------------------------------------------
__global__ __launch_bounds__(TPB) void k_tohalf(const float* __restrict__ x,
                                               __half* __restrict__ x16,
                                               int count4) {
  int i = blockIdx.x * TPB + threadIdx.x;
  if (i >= count4) return;
  float4 v = reinterpret_cast<const float4*>(x)[i];
  __half2 a = __floats2half2_rn(v.x, v.y);
  __half2 b = __floats2half2_rn(v.z, v.w);
  uint2 o;
  o.x = *reinterpret_cast<unsigned*>(&a);
  o.y = *reinterpret_cast<unsigned*>(&b);
  reinterpret_cast<uint2*>(x16)[i] = o;
}

__device__ __forceinline__ float4 up4(uint2 v) {
  float2 fa = __half22float2(*reinterpret_cast<__half2*>(&v.x));
  float2 fb = __half22float2(*reinterpret_cast<__half2*>(&v.y));
  return make_float4(fa.x, fa.y, fb.x, fb.y);
}

// ---- sparse prop (fp16 gather): y = alpha*L.x16 + beta*prev (f32) ---------
// lane = (node, feature-quad): 8 lanes/node, 8 nodes/wave, 32 nodes/block.
// Serial edge walk, 4 unrolled gather chains; NO cross-lane reduce.
__global__ __launch_bounds__(TPB) void k_prop16(
    const __half* __restrict__ x16, const int* __restrict__ rp,
    const uint2* __restrict__ epk, const float* __restrict__ prev, float alpha,
    float beta, float* __restrict__ yout, __half* __restrict__ y16, int n) {
  int tid = threadIdx.x;
  int node = blockIdx.x * 32 + (tid >> 3);
  if (node >= n) return;
  int q = tid & 7;  // feature quad: features [4q, 4q+4)
  const __half* xr = x16 + (q << 2);
  int b = rp[node], e = rp[node + 1];
  float4 a0 = make_float4(0.f, 0.f, 0.f, 0.f);
  float4 a1 = a0, a2 = a0, a3 = a0;
  for (int t = b; t < e; t += 4) {  // segments padded to x16 (4 | 16)
    uint2 e0 = epk[t];
    uint2 e1 = epk[t + 1];
    uint2 e2 = epk[t + 2];
    uint2 e3 = epk[t + 3];
    uint2 v0 = *reinterpret_cast<const uint2*>(xr + (size_t)e0.x * 32);
    uint2 v1 = *reinterpret_cast<const uint2*>(xr + (size_t)e1.x * 32);
    uint2 v2 = *reinterpret_cast<const uint2*>(xr + (size_t)e2.x * 32);
    uint2 v3 = *reinterpret_cast<const uint2*>(xr + (size_t)e3.x * 32);
    float n0 = __uint_as_float(e0.y), n1 = __uint_as_float(e1.y);
    float n2 = __uint_as_float(e2.y), n3 = __uint_as_float(e3.y);
    float4 x0 = up4(v0), x1 = up4(v1), x2 = up4(v2), x3 = up4(v3);
    a0.x = fmaf(n0, x0.x, a0.x);
    a0.y = fmaf(n0, x0.y, a0.y);
    a0.z = fmaf(n0, x0.z, a0.z);
    a0.w = fmaf(n0, x0.w, a0.w);
    a1.x = fmaf(n1, x1.x, a1.x);
    a1.y = fmaf(n1, x1.y, a1.y);
    a1.z = fmaf(n1, x1.z, a1.z);
    a1.w = fmaf(n1, x1.w, a1.w);
    a2.x = fmaf(n2, x2.x, a2.x);
    a2.y = fmaf(n2, x2.y, a2.y);
    a2.z = fmaf(n2, x2.z, a2.z);
    a2.w = fmaf(n2, x2.w, a2.w);
    a3.x = fmaf(n3, x3.x, a3.x);
    a3.y = fmaf(n3, x3.y, a3.y);
    a3.z = fmaf(n3, x3.z, a3.z);
    a3.w = fmaf(n3, x3.w, a3.w);
  }
  float4 r;
  r.x = alpha * ((a0.x + a2.x) + (a1.x + a3.x));
  r.y = alpha * ((a0.y + a2.y) + (a1.y + a3.y));
  r.z = alpha * ((a0.z + a2.z) + (a1.z + a3.z));
  r.w = alpha * ((a0.w + a2.w) + (a1.w + a3.w));
  size_t ob = (size_t)node * 32 + (q << 2);
  if (prev != nullptr) {
    const float4 pv = *reinterpret_cast<const float4*>(&prev[ob]);
    r.x = fmaf(beta, pv.x, r.x);
    r.y = fmaf(beta, pv.y, r.y);
    r.z = fmaf(beta, pv.z, r.z);
    r.w = fmaf(beta, pv.w, r.w);
  }
  *reinterpret_cast<float4*>(&yout[ob]) = r;
  if (y16 != nullptr) {
    __half2 h0 = __floats2half2_rn(r.x, r.y);
    __half2 h1 = __floats2half2_rn(r.z, r.w);
    uint2 o;
    o.x = *reinterpret_cast<unsigned*>(&h0);
    o.y = *reinterpret_cast<unsigned*>(&h1);
    *reinterpret_cast<uint2*>(&y16[ob]) = o;
  }
}

// ---- weight prep: wts[w][g3][hh][k] (wave-sliced), be[g3*32+h] ------------
__global__ __launch_bounds__(TPB) void k_build_wt(
    const float* __restrict__ Wx, const float* __restrict__ bx,
    const float* __restrict__ bh, const float* __restrict__ bb,
    float* __restrict__ wts, float* __restrict__ be) {
  int idx = blockIdx.x * TPB + threadIdx.x;
  if (idx < 96 * 160) {
    int jj = idx / 160, k = idx % 160;
    int w = jj / 24, r = jj % 24;
    int g3 = r >> 3, hh = r & 7;
    int h = w * 8 + hh;
    int kk = k >> 5, i = k & 31;
    int g = (g3 == 0) ? 0 : (g3 == 1 ? 2 : 3);
    wts[idx] = Wx[((g * 5 + kk) * 32 + i) * 32 + h];
  }
  if (idx < 96) {
    int g3 = idx >> 5, h = idx & 31;
    int g = (g3 == 0) ? 0 : (g3 == 1 ? 2 : 3);
    be[idx] = bx[g * 32 + h] + bh[g * 32 + h] + bb[g * 32 + h];
  }
}

// ---- head collapse: w_eff = hw1@hw2@hw3@hw4, b_eff similarly --------------
__global__ void k_head_setup(
    const float* __restrict__ hw1, const float* __restrict__ hb1,
    const float* __restrict__ hw2, const float* __restrict__ hb2,
    const float* __restrict__ hw3, const float* __restrict__ hb3,
    const float* __restrict__ hw4, const float* __restrict__ hb4,
    float* __restrict__ weff) {
  int a = threadIdx.x;
  if (a < 32) {
    float w12[8];
    for (int c = 0; c < 8; ++c) {
      float s = 0.f;
      for (int b = 0; b < 16; ++b) s += hw1[a * 16 + b] * hw2[b * 8 + c];
      w12[c] = s;
    }
    float w123[4];
    for (int d = 0; d < 4; ++d) {
      float s = 0.f;
      for (int c = 0; c < 8; ++c) s += w12[c] * hw3[c * 4 + d];
      w123[d] = s;
    }
    float s = 0.f;
    for (int d = 0; d < 4; ++d) s += w123[d] * hw4[d];
    weff[a] = s;
  }
  if (a == 32) {
    float t2[8];
    for (int c = 0; c < 8; ++c) {
      float s = hb2[c];
      for (int b = 0; b < 16; ++b) s += hb1[b] * hw2[b * 8 + c];
      t2[c] = s;
    }
    float t3[4];
    for (int d = 0; d < 4; ++d) {
      float s = hb3[d];
      for (int c = 0; c < 8; ++c) s += t2[c] * hw3[c * 4 + d];
      t3[d] = s;
    }
    float s = hb4[0];
    for (int d = 0; d < 4; ++d) s += t3[d] * hw4[d];
    weff[32] = s;
  }
}

// ---- fused gates: [50000 x 160] @ [160 x 96] + LSTM gate math + ReLU ------
// 256 threads = 4 waves, 64 nodes; lane = node; wave w owns h in [8w,8w+8).
// Weights staged in LDS per k-half; inner-loop reads are wave-uniform
// ds_read_b128 broadcasts. Layer1: H (f32) + H16. Layer2: fused head -> out.
__global__ __launch_bounds__(256) void k_gates(
    const float* __restrict__ T0, const float* __restrict__ T1,
    const float* __restrict__ T2, const float* __restrict__ T3,
    const float* __restrict__ T4, const float* __restrict__ wts,
    const float* __restrict__ be, const float* __restrict__ wc2,
    float* __restrict__ Hout, __half* __restrict__ H16,
    const float* __restrict__ weff, float* __restrict__ outHead, int n) {
  __shared__ float Wl[96 * 80];  // [row=w*24+g*8+hh][80] current k-half
  __shared__ float Tl[64][84];   // k-half of node T-rows
  __shared__ float Hl[64][33];
  int tid = threadIdx.x;
  int base = blockIdx.x * 64;
  int w = tid >> 6;
  int lane = tid & 63;

  float acc[3][8];
#pragma unroll
  for (int g = 0; g < 3; ++g)
#pragma unroll
    for (int hh = 0; hh < 8; ++hh) acc[g][hh] = 0.f;

  for (int half = 0; half < 2; ++half) {
    if (half) __syncthreads();  // drain half-0 readers before restaging
    for (int i = tid; i < 7680; i += 256)
      Wl[i] = wts[(i / 80) * 160 + half * 80 + (i % 80)];
    for (int i = tid; i < 1280; i += 256) {  // 64 nodes x 20 k-quads
      int node = i / 20, qk = i % 20;
      int gk = half * 80 + qk * 4;
      int mat = gk >> 5, f = gk & 31;
      const float* Tp = (mat == 0) ? T0 : (mat == 1) ? T1 : (mat == 2) ? T2
                        : (mat == 3) ? T3 : T4;
      int gn = base + node;
      float4 v = make_float4(0.f, 0.f, 0.f, 0.f);
      if (gn < n) v = *reinterpret_cast<const float4*>(&Tp[gn * 32 + f]);
      *reinterpret_cast<float4*>(&Tl[node][qk * 4]) = v;
    }
    __syncthreads();

    const float* wpb = &Wl[w * 24 * 80];  // wave's [3][8][80] slice
    for (int k4 = 0; k4 < 20; ++k4) {
      const float4 t = *reinterpret_cast<const float4*>(&Tl[lane][k4 * 4]);
#pragma unroll
      for (int g = 0; g < 3; ++g)
#pragma unroll
        for (int hh = 0; hh < 8; ++hh) {
          const float4 wv = *reinterpret_cast<const float4*>(
              &wpb[(g * 8 + hh) * 80 + k4 * 4]);
          float a = acc[g][hh];
          a = fmaf(t.x, wv.x, a);
          a = fmaf(t.y, wv.y, a);
          a = fmaf(t.z, wv.z, a);
          a = fmaf(t.w, wv.w, a);
          acc[g][hh] = a;
        }
    }
  }

  float hv[8];
#pragma unroll
  for (int hh = 0; hh < 8; ++hh) {
    int h = w * 8 + hh;
    float pi = acc[0][hh] + be[h];
    float pc = acc[1][hh] + be[32 + h];
    float po = acc[2][hh] + be[64 + h];
    float I = 1.f / (1.f + expf(-pi));
    float Cn = I * tanhf(pc);
    float O = 1.f / (1.f + expf(-(po + wc2[h] * Cn)));
    hv[hh] = fmaxf(O * tanhf(Cn), 0.f);
  }

  if (outHead != nullptr) {
    // fused head: partial dot per lane, cross-wave reduce via Hl
    float part = 0.f;
#pragma unroll
    for (int hh = 0; hh < 8; ++hh) part = fmaf(hv[hh], weff[w * 8 + hh], part);
    Hl[lane][w] = part;
    __syncthreads();
    if (tid < 64) {
      int gn = base + tid;
      if (gn < n)
        outHead[gn] =
            (Hl[tid][0] + Hl[tid][1]) + (Hl[tid][2] + Hl[tid][3]) + weff[32];
    }
  } else {
#pragma unroll
    for (int hh = 0; hh < 8; ++hh) Hl[lane][w * 8 + hh] = hv[hh];
    __syncthreads();
    for (int q = tid; q < 2048; q += 256) {  // f32 H, coalesced
      int node = q >> 5, f = q & 31;
      int gn = base + node;
      if (gn < n) Hout[gn * 32 + f] = Hl[node][f];
    }
    for (int q = tid; q < 1024; q += 256) {  // fp16 H for next gather
      int node = q >> 4, fp = q & 15;
      int gn = base + node;
      if (gn < n) {
        __half2 hp = __floats2half2_rn(Hl[node][fp * 2], Hl[node][fp * 2 + 1]);
        *reinterpret_cast<__half2*>(&H16[(size_t)gn * 32 + fp * 2]) = hp;
      }
    }
  }
}

extern "C" void kernel_launch(void* const* d_in, const int* in_sizes, int n_in,
                              void* d_out, int out_size, void* d_ws,
                              size_t ws_size, hipStream_t stream) {
  const float* x = (const float*)d_in[0];
  const int* ei = (const int*)d_in[1];
  const float* ew = (const float*)d_in[2];
  const float* l1_Wx = (const float*)d_in[3];
  const float* l1_bx = (const float*)d_in[4];
  const float* l1_bh = (const float*)d_in[6];
  const float* l1_wc = (const float*)d_in[7];
  const float* l1_b = (const float*)d_in[8];
  const float* l2_Wx = (const float*)d_in[9];
  const float* l2_bx = (const float*)d_in[10];
  const float* l2_bh = (const float*)d_in[12];
  const float* l2_wc = (const float*)d_in[13];
  const float* l2_b = (const float*)d_in[14];
  const float* hw1 = (const float*)d_in[15];
  const float* hb1 = (const float*)d_in[16];
  const float* hw2 = (const float*)d_in[17];
  const float* hb2 = (const float*)d_in[18];
  const float* hw3 = (const float*)d_in[19];
  const float* hb3 = (const float*)d_in[20];
  const float* hw4 = (const float*)d_in[21];
  const float* hb4 = (const float*)d_in[22];

  const int N = in_sizes[0] / 32;
  const int E = in_sizes[1] / 2;
  const size_t EPAD = (size_t)E + 16 * (size_t)N;  // padded CSR capacity

  // workspace carve-out (256B aligned)
  char* w = (char*)d_ws;
  auto alloc = [&](size_t bytes) -> void* {
    void* p = (void*)w;
    w += (bytes + 255) & ~(size_t)255;
    return p;
  };
  float* dinv = (float*)alloc((size_t)N * 4);
  int* cnt = (int*)alloc((size_t)N * 4);
  int* rp = (int*)alloc((size_t)(N + 1) * 4);
  int* excl = (int*)alloc((size_t)N * 4);
  int* bsum = (int*)alloc(256 * 4);
  int* dcnt = (int*)alloc(512 * 4);  // contiguous with scnt: single memset
  int* scnt = (int*)alloc(512 * 4);
  uint2* epk = (uint2*)alloc(EPAD * 8);
  float* T1 = (float*)alloc((size_t)N * 32 * 4);
  float* T2 = (float*)alloc((size_t)N * 32 * 4);
  float* T3 = (float*)alloc((size_t)N * 32 * 4);
  float* T4 = (float*)alloc((size_t)N * 32 * 4);
  float* H1 = (float*)alloc((size_t)N * 32 * 4);
  float* H2 = (float*)alloc((size_t)N * 32 * 4);  // arena tail (unused now)
  float* Wt1 = (float*)alloc(160 * 96 * 4);
  float* be1 = (float*)alloc(96 * 4);
  float* Wt2 = (float*)alloc(160 * 96 * 4);
  float* be2 = (float*)alloc(96 * 4);
  float* weff = (float*)alloc(40 * 4);
  __half* x16 = (__half*)alloc((size_t)N * 32 * 2);
  __half* U1 = (__half*)alloc((size_t)N * 32 * 2);
  __half* U2 = (__half*)alloc((size_t)N * 32 * 2);
  __half* h16 = (__half*)alloc((size_t)N * 32 * 2);
  (void)H2;
  // arenas overlay T/H buffers (dead until props): NB*CAP*8 = 18.82MB each
  uint2* arS = (uint2*)T1;
  uint2* arD = (uint2*)T4;

  const int gBK = (E + EPB - 1) / EPB;
  const int gN = (N + TPB - 1) / TPB;
  const int gP = (N + 31) / 32;
  const int gG = (N + 63) / 64;
  const int gH = (N * 8 + TPB - 1) / TPB;

  hipMemsetAsync(dcnt, 0, 1024 * 4, stream);  // dcnt + scnt
  hipMemsetAsync(epk, 0, EPAD * 8, stream);   // zero pads

  // CSR build (two-level LDS counting sort)
  k_bucket<<<gBK, 512, 0, stream>>>(ei, ew, dcnt, scnt, arD, arS, E);
  k_degcnt<<<NB, TPB, 0, stream>>>(arS, scnt, arD, dcnt, dinv, cnt, N);
  k_scan1<<<gN, TPB, 0, stream>>>(cnt, excl, bsum, N);
  k_scan2<<<1, TPB, 0, stream>>>(bsum, gN);
  k_scan3<<<gN, TPB, 0, stream>>>(excl, bsum, cnt, rp, N);
  k_csr<<<NB, TPB, 0, stream>>>(arD, dcnt, rp, dinv, epk, N);

  // weight prep + fp16 x table
  k_build_wt<<<60, TPB, 0, stream>>>(l1_Wx, l1_bx, l1_bh, l1_b, Wt1, be1);
  k_build_wt<<<60, TPB, 0, stream>>>(l2_Wx, l2_bx, l2_bh, l2_b, Wt2, be2);
  k_head_setup<<<1, 64, 0, stream>>>(hw1, hb1, hw2, hb2, hw3, hb3, hw4, hb4,
                                     weff);
  k_tohalf<<<gH, TPB, 0, stream>>>(x, x16, N * 8);

  // layer 1 (T0 = x)
  k_prop16<<<gP, TPB, 0, stream>>>(x16, rp, epk, nullptr, 1.f, 0.f, T1, U1, N);
  k_prop16<<<gP, TPB, 0, stream>>>(U1, rp, epk, x, 2.f, -1.f, T2, U2, N);
  k_prop16<<<gP, TPB, 0, stream>>>(U2, rp, epk, T1, 2.f, -1.f, T3, U1, N);
  k_prop16<<<gP, TPB, 0, stream>>>(U1, rp, epk, T2, 2.f, -1.f, T4, nullptr, N);
  k_gates<<<gG, 256, 0, stream>>>(x, T1, T2, T3, T4, Wt1, be1, l1_wc + 64, H1,
                                  h16, nullptr, nullptr, N);

  // layer 2 (T0 = H1)
  k_prop16<<<gP, TPB, 0, stream>>>(h16, rp, epk, nullptr, 1.f, 0.f, T1, U1, N);
  k_prop16<<<gP, TPB, 0, stream>>>(U1, rp, epk, H1, 2.f, -1.f, T2, U2, N);
  k_prop16<<<gP, TPB, 0, stream>>>(U2, rp, epk, T1, 2.f, -1.f, T3, U1, N);
  k_prop16<<<gP, TPB, 0, stream>>>(U1, rp, epk, T2, 2.f, -1.f, T4, nullptr, N);
  k_gates<<<gG, 256, 0, stream>>>(H1, T1, T2, T3, T4, Wt2, be2, l2_wc + 64,
                                  nullptr, nullptr, weff, (float*)d_out, N);
}

// Round 11
// 406.686 us; speedup vs baseline: 1.2368x; 1.2368x over previous
//
#include <hip/hip_runtime.h>
#include <hip/hip_fp16.h>
#include <math.h>

// ---------------------------------------------------------------------------
// RecurrentGCN: 2x GConvLSTM(Cheb K=5) + ReLU + collapsed 4-linear head.
// R11 changes:
//  - k_gates -> k_gates_mfma: [50000x160]@[160x96] on matrix cores
//    (v_mfma_f32_16x16x16_f16, 60 MFMA/wave vs 3840 VALU-FMA). R10 post-
//    mortem: all VALU variants bound at 65-154us by operand movement.
//    A = fp16 node tables (props' outputs); B = pre-packed fragments (30KB,
//    L2-resident, per-lane-distinct loads); no main-loop barriers/LDS.
//  - fp16 tables deduplicated: x16, t16a..d, h16 (one per T matrix).
// ---------------------------------------------------------------------------

#define TPB 256
#define PADM 15    // segment pad: round up to multiple of 16
#define BW 128     // nodes per bucket
#define NB 391     // ceil(50000/128)
#define CAP 6016   // per-bucket arena capacity
#define EPB 8192   // edges per k_bucket block

typedef _Float16 f16x4 __attribute__((ext_vector_type(4)));
typedef float f32x4 __attribute__((ext_vector_type(4)));

// ---- bucketing: one read pass, both src- and dst-bucketed arenas ----------
__global__ __launch_bounds__(512) void k_bucket(
    const int* __restrict__ ei, const float* __restrict__ ew,
    int* __restrict__ dcnt, int* __restrict__ scnt, uint2* __restrict__ arD,
    uint2* __restrict__ arS, int E) {
  __shared__ int hd[NB], hs[NB];
  __shared__ int cd[NB], cs[NB];
  int tid = threadIdx.x;
  int base = blockIdx.x * EPB;
  int end = min(base + EPB, E);
  for (int j = tid; j < NB; j += 512) {
    hd[j] = 0;
    hs[j] = 0;
  }
  __syncthreads();
  for (int i = base + tid; i < end; i += 512) {
    int s = ei[i], d = ei[E + i];
    atomicAdd(&hs[s >> 7], 1);
    atomicAdd(&hd[d >> 7], 1);
  }
  __syncthreads();
  for (int j = tid; j < NB; j += 512) {
    cd[j] = (hd[j] > 0) ? atomicAdd(&dcnt[j], hd[j]) : 0;
    cs[j] = (hs[j] > 0) ? atomicAdd(&scnt[j], hs[j]) : 0;
  }
  __syncthreads();
  for (int i = base + tid; i < end; i += 512) {
    int s = ei[i], d = ei[E + i];
    unsigned wbits = __float_as_uint(ew[i]);
    int bs = s >> 7, bd = d >> 7;
    int ps = atomicAdd(&cs[bs], 1);
    int pd = atomicAdd(&cd[bd], 1);
    if (ps < CAP) arS[(size_t)bs * CAP + ps] = make_uint2((unsigned)s, wbits);
    if (pd < CAP)
      arD[(size_t)bd * CAP + pd] =
          make_uint2((unsigned)s | ((unsigned)(d & 127) << 16), wbits);
  }
}

// ---- per-bucket degree (arS) + in-degree counts (arD), merged -------------
__global__ __launch_bounds__(TPB) void k_degcnt(
    const uint2* __restrict__ arS, const int* __restrict__ scnt,
    const uint2* __restrict__ arD, const int* __restrict__ dcnt,
    float* __restrict__ dinv, int* __restrict__ cnt, int N) {
  __shared__ float dacc[BW];
  __shared__ int c[BW];
  int b = blockIdx.x, tid = threadIdx.x;
  if (tid < BW) {
    dacc[tid] = 0.f;
    c[tid] = 0;
  }
  __syncthreads();
  int nbs = scnt[b];
  const uint2* ps = arS + (size_t)b * CAP;
  for (int i = tid; i < nbs; i += TPB) {
    uint2 e = ps[i];
    atomicAdd(&dacc[e.x & 127], __uint_as_float(e.y));
  }
  int nbd = dcnt[b];
  const uint2* pd = arD + (size_t)b * CAP;
  for (int i = tid; i < nbd; i += TPB) {
    atomicAdd(&c[(pd[i].x >> 16) & 127], 1);
  }
  __syncthreads();
  int node = b * BW + tid;
  if (tid < BW && node < N) {
    float dg = dacc[tid];
    dinv[node] = (dg > 0.f) ? 1.0f / sqrtf(fmaxf(dg, 1e-12f)) : 0.f;
    cnt[node] = c[tid];
  }
}

// ---- 3-kernel exclusive scan of padded counts -----------------------------
__global__ __launch_bounds__(TPB) void k_scan1(
    const int* __restrict__ cnt, int* __restrict__ excl, int* __restrict__ bsum,
    int n) {
  __shared__ int sh[TPB];
  int tid = threadIdx.x;
  int i = blockIdx.x * TPB + tid;
  int v = (i < n) ? ((cnt[i] + PADM) & ~PADM) : 0;
  sh[tid] = v;
  __syncthreads();
  for (int off = 1; off < TPB; off <<= 1) {
    int t = (tid >= off) ? sh[tid - off] : 0;
    __syncthreads();
    sh[tid] += t;
    __syncthreads();
  }
  if (i < n) excl[i] = sh[tid] - v;
  if (tid == TPB - 1) bsum[blockIdx.x] = sh[TPB - 1];
}

__global__ __launch_bounds__(TPB) void k_scan2(int* __restrict__ bsum, int nb) {
  __shared__ int sh[TPB];
  int tid = threadIdx.x;
  int v = (tid < nb) ? bsum[tid] : 0;
  sh[tid] = v;
  __syncthreads();
  for (int off = 1; off < TPB; off <<= 1) {
    int t = (tid >= off) ? sh[tid - off] : 0;
    __syncthreads();
    sh[tid] += t;
    __syncthreads();
  }
  if (tid < nb) bsum[tid] = sh[tid] - v;
}

__global__ __launch_bounds__(TPB) void k_scan3(
    const int* __restrict__ excl, const int* __restrict__ bsum,
    const int* __restrict__ cnt, int* __restrict__ rp, int n) {
  int i = blockIdx.x * TPB + threadIdx.x;
  if (i < n) {
    int r = excl[i] + bsum[i >> 8];
    rp[i] = r;
    if (i == n - 1) rp[n] = r + ((cnt[i] + PADM) & ~PADM);
  }
}

// ---- final CSR scatter: LDS cursors + fused norm --------------------------
__global__ __launch_bounds__(TPB) void k_csr(
    const uint2* __restrict__ arD, const int* __restrict__ dcnt,
    const int* __restrict__ rp, const float* __restrict__ dinv,
    uint2* __restrict__ epk, int N) {
  __shared__ int cur[BW];
  __shared__ float dloc[BW];
  int b = blockIdx.x, tid = threadIdx.x;
  int node = b * BW + tid;
  if (tid < BW) {
    cur[tid] = (node < N) ? rp[node] : 0;
    dloc[tid] = (node < N) ? dinv[node] : 0.f;
  }
  __syncthreads();
  int nb = dcnt[b];
  const uint2* p = arD + (size_t)b * CAP;
  for (int i = tid; i < nb; i += TPB) {
    uint2 e = p[i];
    int src = e.x & 0xFFFF;
    int dl = (e.x >> 16) & 127;
    float nv = -dinv[src] * __uint_as_float(e.y) * dloc[dl];
    int pos = atomicAdd(&cur[dl], 1);
    epk[pos] = make_uint2((unsigned)src, __float_as_uint(nv));
  }
}

// ---- f32 -> fp16 table build ----------------------------------------------
__global__ __launch_bounds__(TPB) void k_tohalf(const float* __restrict__ x,
                                               __half* __restrict__ x16,
                                               int count4) {
  int i = blockIdx.x * TPB + threadIdx.x;
  if (i >= count4) return;
  float4 v = reinterpret_cast<const float4*>(x)[i];
  __half2 a = __floats2half2_rn(v.x, v.y);
  __half2 b = __floats2half2_rn(v.z, v.w);
  uint2 o;
  o.x = *reinterpret_cast<unsigned*>(&a);
  o.y = *reinterpret_cast<unsigned*>(&b);
  reinterpret_cast<uint2*>(x16)[i] = o;
}

__device__ __forceinline__ float4 up4(uint2 v) {
  float2 fa = __half22float2(*reinterpret_cast<__half2*>(&v.x));
  float2 fb = __half22float2(*reinterpret_cast<__half2*>(&v.y));
  return make_float4(fa.x, fa.y, fb.x, fb.y);
}

// ---- sparse prop (fp16 gather): y = alpha*L.x16 + beta*prev (f32) ---------
// lane = (node, feature-quad): 8 lanes/node, 32 nodes/block. Serial edge
// walk, 4 unrolled gather chains; no cross-lane reduce. Writes f32 + fp16.
__global__ __launch_bounds__(TPB) void k_prop16(
    const __half* __restrict__ x16, const int* __restrict__ rp,
    const uint2* __restrict__ epk, const float* __restrict__ prev, float alpha,
    float beta, float* __restrict__ yout, __half* __restrict__ y16, int n) {
  int tid = threadIdx.x;
  int node = blockIdx.x * 32 + (tid >> 3);
  if (node >= n) return;
  int q = tid & 7;  // feature quad: features [4q, 4q+4)
  const __half* xr = x16 + (q << 2);
  int b = rp[node], e = rp[node + 1];
  float4 a0 = make_float4(0.f, 0.f, 0.f, 0.f);
  float4 a1 = a0, a2 = a0, a3 = a0;
  for (int t = b; t < e; t += 4) {  // segments padded to x16 (4 | 16)
    uint2 e0 = epk[t];
    uint2 e1 = epk[t + 1];
    uint2 e2 = epk[t + 2];
    uint2 e3 = epk[t + 3];
    uint2 v0 = *reinterpret_cast<const uint2*>(xr + (size_t)e0.x * 32);
    uint2 v1 = *reinterpret_cast<const uint2*>(xr + (size_t)e1.x * 32);
    uint2 v2 = *reinterpret_cast<const uint2*>(xr + (size_t)e2.x * 32);
    uint2 v3 = *reinterpret_cast<const uint2*>(xr + (size_t)e3.x * 32);
    float n0 = __uint_as_float(e0.y), n1 = __uint_as_float(e1.y);
    float n2 = __uint_as_float(e2.y), n3 = __uint_as_float(e3.y);
    float4 x0 = up4(v0), x1 = up4(v1), x2 = up4(v2), x3 = up4(v3);
    a0.x = fmaf(n0, x0.x, a0.x);
    a0.y = fmaf(n0, x0.y, a0.y);
    a0.z = fmaf(n0, x0.z, a0.z);
    a0.w = fmaf(n0, x0.w, a0.w);
    a1.x = fmaf(n1, x1.x, a1.x);
    a1.y = fmaf(n1, x1.y, a1.y);
    a1.z = fmaf(n1, x1.z, a1.z);
    a1.w = fmaf(n1, x1.w, a1.w);
    a2.x = fmaf(n2, x2.x, a2.x);
    a2.y = fmaf(n2, x2.y, a2.y);
    a2.z = fmaf(n2, x2.z, a2.z);
    a2.w = fmaf(n2, x2.w, a2.w);
    a3.x = fmaf(n3, x3.x, a3.x);
    a3.y = fmaf(n3, x3.y, a3.y);
    a3.z = fmaf(n3, x3.z, a3.z);
    a3.w = fmaf(n3, x3.w, a3.w);
  }
  float4 r;
  r.x = alpha * ((a0.x + a2.x) + (a1.x + a3.x));
  r.y = alpha * ((a0.y + a2.y) + (a1.y + a3.y));
  r.z = alpha * ((a0.z + a2.z) + (a1.z + a3.z));
  r.w = alpha * ((a0.w + a2.w) + (a1.w + a3.w));
  size_t ob = (size_t)node * 32 + (q << 2);
  if (prev != nullptr) {
    const float4 pv = *reinterpret_cast<const float4*>(&prev[ob]);
    r.x = fmaf(beta, pv.x, r.x);
    r.y = fmaf(beta, pv.y, r.y);
    r.z = fmaf(beta, pv.z, r.z);
    r.w = fmaf(beta, pv.w, r.w);
  }
  *reinterpret_cast<float4*>(&yout[ob]) = r;
  __half2 h0 = __floats2half2_rn(r.x, r.y);
  __half2 h1 = __floats2half2_rn(r.z, r.w);
  uint2 o;
  o.x = *reinterpret_cast<unsigned*>(&h0);
  o.y = *reinterpret_cast<unsigned*>(&h1);
  *reinterpret_cast<uint2*>(&y16[ob]) = o;
}

// ---- weight prep: B fragments for 16x16x16 f16 MFMA + fused bias ----------
// Bf[t][s][l][j] = W[k=16s+4*(l>>4)+j][c=16t+(l&15)], W[k][c]=Wx pruned
// (c = g3*32+h; gates kept i,c,o). 15360 halves = 30KB.
__global__ __launch_bounds__(TPB) void k_build_wt(
    const float* __restrict__ Wx, const float* __restrict__ bx,
    const float* __restrict__ bh, const float* __restrict__ bb,
    __half* __restrict__ Bf, float* __restrict__ be) {
  int idx = blockIdx.x * TPB + threadIdx.x;
  if (idx < 15360) {
    int t = idx / 2560, r1 = idx % 2560;
    int s = r1 / 256, r2 = r1 % 256;
    int l = r2 / 4, j = r2 % 4;
    int k = s * 16 + (l >> 4) * 4 + j;
    int c = t * 16 + (l & 15);
    int g3 = c >> 5, h = c & 31;
    int g = (g3 == 0) ? 0 : (g3 == 1 ? 2 : 3);
    int kk = k >> 5, i = k & 31;
    Bf[idx] = __float2half(Wx[((g * 5 + kk) * 32 + i) * 32 + h]);
  }
  if (idx < 96) {
    int g3 = idx >> 5, h = idx & 31;
    int g = (g3 == 0) ? 0 : (g3 == 1 ? 2 : 3);
    be[idx] = bx[g * 32 + h] + bh[g * 32 + h] + bb[g * 32 + h];
  }
}

// ---- head collapse: w_eff = hw1@hw2@hw3@hw4, b_eff similarly --------------
__global__ void k_head_setup(
    const float* __restrict__ hw1, const float* __restrict__ hb1,
    const float* __restrict__ hw2, const float* __restrict__ hb2,
    const float* __restrict__ hw3, const float* __restrict__ hb3,
    const float* __restrict__ hw4, const float* __restrict__ hb4,
    float* __restrict__ weff) {
  int a = threadIdx.x;
  if (a < 32) {
    float w12[8];
    for (int c = 0; c < 8; ++c) {
      float s = 0.f;
      for (int b = 0; b < 16; ++b) s += hw1[a * 16 + b] * hw2[b * 8 + c];
      w12[c] = s;
    }
    float w123[4];
    for (int d = 0; d < 4; ++d) {
      float s = 0.f;
      for (int c = 0; c < 8; ++c) s += w12[c] * hw3[c * 4 + d];
      w123[d] = s;
    }
    float s = 0.f;
    for (int d = 0; d < 4; ++d) s += w123[d] * hw4[d];
    weff[a] = s;
  }
  if (a == 32) {
    float t2[8];
    for (int c = 0; c < 8; ++c) {
      float s = hb2[c];
      for (int b = 0; b < 16; ++b) s += hb1[b] * hw2[b * 8 + c];
      t2[c] = s;
    }
    float t3[4];
    for (int d = 0; d < 4; ++d) {
      float s = hb3[d];
      for (int c = 0; c < 8; ++c) s += t2[c] * hw3[c * 4 + d];
      t3[d] = s;
    }
    float s = hb4[0];
    for (int d = 0; d < 4; ++d) s += t3[d] * hw4[d];
    weff[32] = s;
  }
}

// ---- fused gates on matrix cores ------------------------------------------
// 256 thr = 4 waves; wave w: nodes [base+16w, +16). Per wave: 10 ksteps x
// 6 n-tiles of v_mfma_f32_16x16x16_f16. A: lane holds T[node=base16+(l&15)]
// [k=16s+4*(l>>4)+j] from fp16 tables; B: pre-packed fragments; D: col=l&15,
// row=4*(l>>4)+reg (m89-verified). Epilogue: gate math (+head on layer 2).
__global__ __launch_bounds__(256) void k_gates_mfma(
    const __half* __restrict__ tab0, const __half* __restrict__ tab1,
    const __half* __restrict__ tab2, const __half* __restrict__ tab3,
    const __half* __restrict__ tab4, const __half* __restrict__ Bf,
    const float* __restrict__ be, const float* __restrict__ wc2,
    float* __restrict__ Hout, __half* __restrict__ H16,
    const float* __restrict__ weff, float* __restrict__ outHead, int n) {
  __shared__ float Hl[64][33];
  __shared__ float P[64][17];
  int tid = threadIdx.x;
  int w = tid >> 6, l = tid & 63;
  int lo = l & 15, hi = l >> 4;
  int base16 = blockIdx.x * 64 + w * 16;
  int anode = base16 + lo;
  if (anode >= n) anode = n - 1;  // clamp loads; stores guarded below

  f32x4 acc[6];
#pragma unroll
  for (int t = 0; t < 6; ++t) acc[t] = (f32x4){0.f, 0.f, 0.f, 0.f};

#pragma unroll
  for (int s = 0; s < 10; ++s) {
    const __half* tp = (s < 2) ? tab0 : (s < 4) ? tab1 : (s < 6) ? tab2
                       : (s < 8) ? tab3 : tab4;
    f16x4 a = *reinterpret_cast<const f16x4*>(tp + (size_t)anode * 32 +
                                              (s & 1) * 16 + hi * 4);
#pragma unroll
    for (int t = 0; t < 6; ++t) {
      f16x4 b =
          *reinterpret_cast<const f16x4*>(Bf + ((t * 10 + s) * 64 + l) * 4);
      acc[t] = __builtin_amdgcn_mfma_f32_16x16x16f16(a, b, acc[t], 0, 0, 0);
    }
  }

#pragma unroll
  for (int r = 0; r < 4; ++r) {
    int nl = w * 16 + hi * 4 + r;  // local node of D row
    float part = 0.f;
#pragma unroll
    for (int u = 0; u < 2; ++u) {
      int h = u * 16 + lo;
      float pi = acc[u][r] + be[h];
      float pc = acc[2 + u][r] + be[32 + h];
      float po = acc[4 + u][r] + be[64 + h];
      float I = 1.f / (1.f + expf(-pi));
      float Cn = I * tanhf(pc);
      float O = 1.f / (1.f + expf(-(po + wc2[h] * Cn)));
      float hv = fmaxf(O * tanhf(Cn), 0.f);
      if (outHead != nullptr)
        part = fmaf(hv, weff[h], part);
      else
        Hl[nl][h] = hv;
    }
    if (outHead != nullptr) P[nl][lo] = part;
  }
  __syncthreads();

  if (outHead != nullptr) {
    if (tid < 64) {
      int gn = blockIdx.x * 64 + tid;
      if (gn < n) {
        float s = weff[32];
#pragma unroll
        for (int c = 0; c < 16; ++c) s += P[tid][c];
        outHead[gn] = s;
      }
    }
  } else {
    for (int q = tid; q < 2048; q += 256) {  // f32 H, coalesced
      int node = q >> 5, f = q & 31;
      int gn = blockIdx.x * 64 + node;
      if (gn < n) Hout[gn * 32 + f] = Hl[node][f];
    }
    for (int q = tid; q < 1024; q += 256) {  // fp16 H for next gather
      int node = q >> 4, fp = q & 15;
      int gn = blockIdx.x * 64 + node;
      if (gn < n) {
        __half2 hp = __floats2half2_rn(Hl[node][fp * 2], Hl[node][fp * 2 + 1]);
        *reinterpret_cast<__half2*>(&H16[(size_t)gn * 32 + fp * 2]) = hp;
      }
    }
  }
}

extern "C" void kernel_launch(void* const* d_in, const int* in_sizes, int n_in,
                              void* d_out, int out_size, void* d_ws,
                              size_t ws_size, hipStream_t stream) {
  const float* x = (const float*)d_in[0];
  const int* ei = (const int*)d_in[1];
  const float* ew = (const float*)d_in[2];
  const float* l1_Wx = (const float*)d_in[3];
  const float* l1_bx = (const float*)d_in[4];
  const float* l1_bh = (const float*)d_in[6];
  const float* l1_wc = (const float*)d_in[7];
  const float* l1_b = (const float*)d_in[8];
  const float* l2_Wx = (const float*)d_in[9];
  const float* l2_bx = (const float*)d_in[10];
  const float* l2_bh = (const float*)d_in[12];
  const float* l2_wc = (const float*)d_in[13];
  const float* l2_b = (const float*)d_in[14];
  const float* hw1 = (const float*)d_in[15];
  const float* hb1 = (const float*)d_in[16];
  const float* hw2 = (const float*)d_in[17];
  const float* hb2 = (const float*)d_in[18];
  const float* hw3 = (const float*)d_in[19];
  const float* hb3 = (const float*)d_in[20];
  const float* hw4 = (const float*)d_in[21];
  const float* hb4 = (const float*)d_in[22];

  const int N = in_sizes[0] / 32;
  const int E = in_sizes[1] / 2;
  const size_t EPAD = (size_t)E + 16 * (size_t)N;  // padded CSR capacity
  const size_t TBL = (size_t)(N + 64) * 32 * 2;    // fp16 table (+pad rows)

  // workspace carve-out (256B aligned)
  char* w = (char*)d_ws;
  auto alloc = [&](size_t bytes) -> void* {
    void* p = (void*)w;
    w += (bytes + 255) & ~(size_t)255;
    return p;
  };
  float* dinv = (float*)alloc((size_t)N * 4);
  int* cnt = (int*)alloc((size_t)N * 4);
  int* rp = (int*)alloc((size_t)(N + 1) * 4);
  int* excl = (int*)alloc((size_t)N * 4);
  int* bsum = (int*)alloc(256 * 4);
  int* dcnt = (int*)alloc(512 * 4);  // contiguous with scnt: single memset
  int* scnt = (int*)alloc(512 * 4);
  uint2* epk = (uint2*)alloc(EPAD * 8);
  float* T1 = (float*)alloc((size_t)N * 32 * 4);
  float* T2 = (float*)alloc((size_t)N * 32 * 4);
  float* T3 = (float*)alloc((size_t)N * 32 * 4);
  float* T4 = (float*)alloc((size_t)N * 32 * 4);
  float* H1 = (float*)alloc((size_t)N * 32 * 4);
  float* H2 = (float*)alloc((size_t)N * 32 * 4);  // arena tail (overlay only)
  __half* Bf1 = (__half*)alloc(15360 * 2);
  float* be1 = (float*)alloc(96 * 4);
  __half* Bf2 = (__half*)alloc(15360 * 2);
  float* be2 = (float*)alloc(96 * 4);
  float* weff = (float*)alloc(40 * 4);
  __half* x16 = (__half*)alloc(TBL);
  __half* h16 = (__half*)alloc(TBL);
  __half* t16a = (__half*)alloc(TBL);
  __half* t16b = (__half*)alloc(TBL);
  __half* t16c = (__half*)alloc(TBL);
  __half* t16d = (__half*)alloc(TBL);
  (void)H2;
  // arenas overlay T/H buffers (dead until props): NB*CAP*8 = 18.82MB each
  uint2* arS = (uint2*)T1;
  uint2* arD = (uint2*)T4;

  const int gBK = (E + EPB - 1) / EPB;
  const int gN = (N + TPB - 1) / TPB;
  const int gP = (N + 31) / 32;
  const int gG = (N + 63) / 64;
  const int gH = (N * 8 + TPB - 1) / TPB;

  hipMemsetAsync(dcnt, 0, 1024 * 4, stream);  // dcnt + scnt
  hipMemsetAsync(epk, 0, EPAD * 8, stream);   // zero pads

  // CSR build (two-level LDS counting sort)
  k_bucket<<<gBK, 512, 0, stream>>>(ei, ew, dcnt, scnt, arD, arS, E);
  k_degcnt<<<NB, TPB, 0, stream>>>(arS, scnt, arD, dcnt, dinv, cnt, N);
  k_scan1<<<gN, TPB, 0, stream>>>(cnt, excl, bsum, N);
  k_scan2<<<1, TPB, 0, stream>>>(bsum, gN);
  k_scan3<<<gN, TPB, 0, stream>>>(excl, bsum, cnt, rp, N);
  k_csr<<<NB, TPB, 0, stream>>>(arD, dcnt, rp, dinv, epk, N);

  // weight prep + fp16 x table
  k_build_wt<<<60, TPB, 0, stream>>>(l1_Wx, l1_bx, l1_bh, l1_b, Bf1, be1);
  k_build_wt<<<60, TPB, 0, stream>>>(l2_Wx, l2_bx, l2_bh, l2_b, Bf2, be2);
  k_head_setup<<<1, 64, 0, stream>>>(hw1, hb1, hw2, hb2, hw3, hb3, hw4, hb4,
                                     weff);
  k_tohalf<<<gH, TPB, 0, stream>>>(x, x16, N * 8);

  // layer 1 (T0 = x)
  k_prop16<<<gP, TPB, 0, stream>>>(x16, rp, epk, nullptr, 1.f, 0.f, T1, t16a,
                                   N);
  k_prop16<<<gP, TPB, 0, stream>>>(t16a, rp, epk, x, 2.f, -1.f, T2, t16b, N);
  k_prop16<<<gP, TPB, 0, stream>>>(t16b, rp, epk, T1, 2.f, -1.f, T3, t16c, N);
  k_prop16<<<gP, TPB, 0, stream>>>(t16c, rp, epk, T2, 2.f, -1.f, T4, t16d, N);
  k_gates_mfma<<<gG, 256, 0, stream>>>(x16, t16a, t16b, t16c, t16d, Bf1, be1,
                                       l1_wc + 64, H1, h16, nullptr, nullptr,
                                       N);

  // layer 2 (T0 = H1)
  k_prop16<<<gP, TPB, 0, stream>>>(h16, rp, epk, nullptr, 1.f, 0.f, T1, t16a,
                                   N);
  k_prop16<<<gP, TPB, 0, stream>>>(t16a, rp, epk, H1, 2.f, -1.f, T2, t16b, N);
  k_prop16<<<gP, TPB, 0, stream>>>(t16b, rp, epk, T1, 2.f, -1.f, T3, t16c, N);
  k_prop16<<<gP, TPB, 0, stream>>>(t16c, rp, epk, T2, 2.f, -1.f, T4, t16d, N);
  k_gates_mfma<<<gG, 256, 0, stream>>>(h16, t16a, t16b, t16c, t16d, Bf2, be2,
                                       l2_wc + 64, nullptr, nullptr, weff,
                                       (float*)d_out, N);
}

// Round 12
// 398.829 us; speedup vs baseline: 1.2611x; 1.0197x over previous
//
#include <hip/hip_runtime.h>
#include <hip/hip_fp16.h>
#include <math.h>

// ---------------------------------------------------------------------------
// RecurrentGCN: 2x GConvLSTM(Cheb K=5) + ReLU + collapsed 4-linear head.
// R12 changes:
//  - k_bucket v2: LDS-staged radix scatter (64KB block arena, LDS hist ->
//    scan -> scatter -> contiguous per-bucket copy-out). R11 post-mortem:
//    random 8B cross-fabric writes capped at ~1.5TB/s, 55us. arS shrunk
//    to 4B fixed-point entries.
//  - fp16-only Chebyshev recurrence: props read prev from fp16 tables and
//    write fp16 only (-12.8MB/prop; gates consume fp16 tables anyway).
//    Explicit epk prefetch: 8 loads in flight per lane.
//  - gates layer-1 emits h16 only (H1 f32 eliminated).
// ---------------------------------------------------------------------------

#define TPB 256
#define PADM 15    // segment pad: round up to multiple of 16
#define BW 128     // nodes per bucket
#define NB 391     // ceil(50000/128)
#define CAP 6016   // per-bucket arena capacity
#define EPB 8192   // edges per k_bucket block
#define DEG_SCALE 16777216.0f  // 2^24 fixed-point for degree weights

typedef _Float16 f16x4 __attribute__((ext_vector_type(4)));
typedef float f32x4 __attribute__((ext_vector_type(4)));

// ---- bucketing v2: LDS-staged radix scatter, coalesced arena writes -------
__global__ __launch_bounds__(512) void k_bucket(
    const int* __restrict__ ei, const float* __restrict__ ew,
    int* __restrict__ dcnt, int* __restrict__ scnt, uint2* __restrict__ arD,
    unsigned* __restrict__ arS, int E) {
  __shared__ uint2 ebuf2[EPB];  // 64 KB staging (uint round reuses low half)
  __shared__ int hist[NB], lofs[NB + 1], gbase[NB], cur[NB];
  __shared__ int sc[512];
  unsigned* ebuf1 = (unsigned*)ebuf2;
  int tid = threadIdx.x;
  int base = blockIdx.x * EPB;
  int end = min(base + EPB, E);
  int nE = end - base;

  // ================= round D (bucket by dst) =================
  for (int j = tid; j < NB; j += 512) hist[j] = 0;
  __syncthreads();
  for (int i = base + tid; i < end; i += 512)
    atomicAdd(&hist[ei[E + i] >> 7], 1);
  __syncthreads();
  int v = (tid < NB) ? hist[tid] : 0;
  sc[tid] = v;
  __syncthreads();
  for (int off = 1; off < 512; off <<= 1) {
    int t = (tid >= off) ? sc[tid - off] : 0;
    __syncthreads();
    sc[tid] += t;
    __syncthreads();
  }
  if (tid < NB) {
    int ex = sc[tid] - v;
    lofs[tid] = ex;
    cur[tid] = ex;
    gbase[tid] = (v > 0) ? atomicAdd(&dcnt[tid], v) : 0;
  }
  if (tid == 0) lofs[NB] = nE;
  __syncthreads();
  for (int i = base + tid; i < end; i += 512) {
    int s = ei[i], d = ei[E + i];
    int p = atomicAdd(&cur[d >> 7], 1);
    ebuf2[p] = make_uint2((unsigned)s | ((unsigned)(d & 127) << 16),
                          __float_as_uint(ew[i]));
  }
  __syncthreads();
  for (int i = tid; i < nE; i += 512) {
    int loJ = 0, hiJ = NB;
    while (hiJ - loJ > 1) {
      int mid = (loJ + hiJ) >> 1;
      if (lofs[mid] <= i) loJ = mid;
      else hiJ = mid;
    }
    int gpos = gbase[loJ] + (i - lofs[loJ]);
    if (gpos < CAP) arD[(size_t)loJ * CAP + gpos] = ebuf2[i];
  }
  __syncthreads();

  // ================= round S (bucket by src, 4B entries) =================
  for (int j = tid; j < NB; j += 512) hist[j] = 0;
  __syncthreads();
  for (int i = base + tid; i < end; i += 512)
    atomicAdd(&hist[ei[i] >> 7], 1);
  __syncthreads();
  v = (tid < NB) ? hist[tid] : 0;
  sc[tid] = v;
  __syncthreads();
  for (int off = 1; off < 512; off <<= 1) {
    int t = (tid >= off) ? sc[tid - off] : 0;
    __syncthreads();
    sc[tid] += t;
    __syncthreads();
  }
  if (tid < NB) {
    int ex = sc[tid] - v;
    lofs[tid] = ex;
    cur[tid] = ex;
    gbase[tid] = (v > 0) ? atomicAdd(&scnt[tid], v) : 0;
  }
  if (tid == 0) lofs[NB] = nE;
  __syncthreads();
  for (int i = base + tid; i < end; i += 512) {
    int s = ei[i];
    unsigned wfix = (unsigned)(ew[i] * DEG_SCALE + 0.5f);
    int p = atomicAdd(&cur[s >> 7], 1);
    ebuf1[p] = ((unsigned)(s & 127) << 25) | wfix;
  }
  __syncthreads();
  for (int i = tid; i < nE; i += 512) {
    int loJ = 0, hiJ = NB;
    while (hiJ - loJ > 1) {
      int mid = (loJ + hiJ) >> 1;
      if (lofs[mid] <= i) loJ = mid;
      else hiJ = mid;
    }
    int gpos = gbase[loJ] + (i - lofs[loJ]);
    if (gpos < CAP) arS[(size_t)loJ * CAP + gpos] = ebuf1[i];
  }
}

// ---- per-bucket degree (arS, fixed-point) + in-degree counts (arD) --------
__global__ __launch_bounds__(TPB) void k_degcnt(
    const unsigned* __restrict__ arS, const int* __restrict__ scnt,
    const uint2* __restrict__ arD, const int* __restrict__ dcnt,
    float* __restrict__ dinv, int* __restrict__ cnt, int N) {
  __shared__ unsigned dacc[BW];
  __shared__ int c[BW];
  int b = blockIdx.x, tid = threadIdx.x;
  if (tid < BW) {
    dacc[tid] = 0u;
    c[tid] = 0;
  }
  __syncthreads();
  int nbs = scnt[b];
  const unsigned* ps = arS + (size_t)b * CAP;
  for (int i = tid; i < nbs; i += TPB) {
    unsigned e = ps[i];
    atomicAdd(&dacc[e >> 25], e & 0x1FFFFFFu);
  }
  int nbd = dcnt[b];
  const uint2* pd = arD + (size_t)b * CAP;
  for (int i = tid; i < nbd; i += TPB) {
    atomicAdd(&c[(pd[i].x >> 16) & 127], 1);
  }
  __syncthreads();
  int node = b * BW + tid;
  if (tid < BW && node < N) {
    unsigned ds = dacc[tid];
    float dg = (float)ds * (1.0f / DEG_SCALE);
    dinv[node] = (ds > 0u) ? 1.0f / sqrtf(fmaxf(dg, 1e-12f)) : 0.f;
    cnt[node] = c[tid];
  }
}

// ---- 3-kernel exclusive scan of padded counts -----------------------------
__global__ __launch_bounds__(TPB) void k_scan1(
    const int* __restrict__ cnt, int* __restrict__ excl, int* __restrict__ bsum,
    int n) {
  __shared__ int sh[TPB];
  int tid = threadIdx.x;
  int i = blockIdx.x * TPB + tid;
  int v = (i < n) ? ((cnt[i] + PADM) & ~PADM) : 0;
  sh[tid] = v;
  __syncthreads();
  for (int off = 1; off < TPB; off <<= 1) {
    int t = (tid >= off) ? sh[tid - off] : 0;
    __syncthreads();
    sh[tid] += t;
    __syncthreads();
  }
  if (i < n) excl[i] = sh[tid] - v;
  if (tid == TPB - 1) bsum[blockIdx.x] = sh[TPB - 1];
}

__global__ __launch_bounds__(TPB) void k_scan2(int* __restrict__ bsum, int nb) {
  __shared__ int sh[TPB];
  int tid = threadIdx.x;
  int v = (tid < nb) ? bsum[tid] : 0;
  sh[tid] = v;
  __syncthreads();
  for (int off = 1; off < TPB; off <<= 1) {
    int t = (tid >= off) ? sh[tid - off] : 0;
    __syncthreads();
    sh[tid] += t;
    __syncthreads();
  }
  if (tid < nb) bsum[tid] = sh[tid] - v;
}

__global__ __launch_bounds__(TPB) void k_scan3(
    const int* __restrict__ excl, const int* __restrict__ bsum,
    const int* __restrict__ cnt, int* __restrict__ rp, int n) {
  int i = blockIdx.x * TPB + threadIdx.x;
  if (i < n) {
    int r = excl[i] + bsum[i >> 8];
    rp[i] = r;
    if (i == n - 1) rp[n] = r + ((cnt[i] + PADM) & ~PADM);
  }
}

// ---- final CSR scatter: LDS cursors + fused norm --------------------------
__global__ __launch_bounds__(TPB) void k_csr(
    const uint2* __restrict__ arD, const int* __restrict__ dcnt,
    const int* __restrict__ rp, const float* __restrict__ dinv,
    uint2* __restrict__ epk, int N) {
  __shared__ int cur[BW];
  __shared__ float dloc[BW];
  int b = blockIdx.x, tid = threadIdx.x;
  int node = b * BW + tid;
  if (tid < BW) {
    cur[tid] = (node < N) ? rp[node] : 0;
    dloc[tid] = (node < N) ? dinv[node] : 0.f;
  }
  __syncthreads();
  int nb = dcnt[b];
  const uint2* p = arD + (size_t)b * CAP;
  for (int i = tid; i < nb; i += TPB) {
    uint2 e = p[i];
    int src = e.x & 0xFFFF;
    int dl = (e.x >> 16) & 127;
    float nv = -dinv[src] * __uint_as_float(e.y) * dloc[dl];
    int pos = atomicAdd(&cur[dl], 1);
    epk[pos] = make_uint2((unsigned)src, __float_as_uint(nv));
  }
}

// ---- f32 -> fp16 table build ----------------------------------------------
__global__ __launch_bounds__(TPB) void k_tohalf(const float* __restrict__ x,
                                               __half* __restrict__ x16,
                                               int count4) {
  int i = blockIdx.x * TPB + threadIdx.x;
  if (i >= count4) return;
  float4 v = reinterpret_cast<const float4*>(x)[i];
  __half2 a = __floats2half2_rn(v.x, v.y);
  __half2 b = __floats2half2_rn(v.z, v.w);
  uint2 o;
  o.x = *reinterpret_cast<unsigned*>(&a);
  o.y = *reinterpret_cast<unsigned*>(&b);
  reinterpret_cast<uint2*>(x16)[i] = o;
}

__device__ __forceinline__ float4 up4(uint2 v) {
  float2 fa = __half22float2(*reinterpret_cast<__half2*>(&v.x));
  float2 fb = __half22float2(*reinterpret_cast<__half2*>(&v.y));
  return make_float4(fa.x, fa.y, fb.x, fb.y);
}

// ---- sparse prop (fp16 in/out): y16 = alpha*L.x16 + beta*prev16 -----------
// lane = (node, feature-quad): 8 lanes/node, 32 nodes/block. Serial edge
// walk, 4 gather chains + epk prefetch one iteration ahead (8 in flight).
__global__ __launch_bounds__(TPB) void k_prop16(
    const __half* __restrict__ xt, const int* __restrict__ rp,
    const uint2* __restrict__ epk, const __half* __restrict__ prev,
    float alpha, float beta, __half* __restrict__ y16, int n) {
  int tid = threadIdx.x;
  int node = blockIdx.x * 32 + (tid >> 3);
  if (node >= n) return;
  int q = tid & 7;  // feature quad: features [4q, 4q+4)
  const __half* xr = xt + (q << 2);
  int b = rp[node], e = rp[node + 1];  // e-b >= 16, multiple of 16
  float4 a0 = make_float4(0.f, 0.f, 0.f, 0.f);
  float4 a1 = a0, a2 = a0, a3 = a0;
  uint2 pe0 = epk[b], pe1 = epk[b + 1], pe2 = epk[b + 2], pe3 = epk[b + 3];
  for (int t = b; t < e; t += 4) {
    uint2 e0 = pe0, e1 = pe1, e2 = pe2, e3 = pe3;
    int t2 = t + 4;
    if (t2 < e) {
      pe0 = epk[t2];
      pe1 = epk[t2 + 1];
      pe2 = epk[t2 + 2];
      pe3 = epk[t2 + 3];
    }
    uint2 v0 = *reinterpret_cast<const uint2*>(xr + (size_t)e0.x * 32);
    uint2 v1 = *reinterpret_cast<const uint2*>(xr + (size_t)e1.x * 32);
    uint2 v2 = *reinterpret_cast<const uint2*>(xr + (size_t)e2.x * 32);
    uint2 v3 = *reinterpret_cast<const uint2*>(xr + (size_t)e3.x * 32);
    float n0 = __uint_as_float(e0.y), n1 = __uint_as_float(e1.y);
    float n2 = __uint_as_float(e2.y), n3 = __uint_as_float(e3.y);
    float4 x0 = up4(v0), x1 = up4(v1), x2 = up4(v2), x3 = up4(v3);
    a0.x = fmaf(n0, x0.x, a0.x);
    a0.y = fmaf(n0, x0.y, a0.y);
    a0.z = fmaf(n0, x0.z, a0.z);
    a0.w = fmaf(n0, x0.w, a0.w);
    a1.x = fmaf(n1, x1.x, a1.x);
    a1.y = fmaf(n1, x1.y, a1.y);
    a1.z = fmaf(n1, x1.z, a1.z);
    a1.w = fmaf(n1, x1.w, a1.w);
    a2.x = fmaf(n2, x2.x, a2.x);
    a2.y = fmaf(n2, x2.y, a2.y);
    a2.z = fmaf(n2, x2.z, a2.z);
    a2.w = fmaf(n2, x2.w, a2.w);
    a3.x = fmaf(n3, x3.x, a3.x);
    a3.y = fmaf(n3, x3.y, a3.y);
    a3.z = fmaf(n3, x3.z, a3.z);
    a3.w = fmaf(n3, x3.w, a3.w);
  }
  float4 r;
  r.x = alpha * ((a0.x + a2.x) + (a1.x + a3.x));
  r.y = alpha * ((a0.y + a2.y) + (a1.y + a3.y));
  r.z = alpha * ((a0.z + a2.z) + (a1.z + a3.z));
  r.w = alpha * ((a0.w + a2.w) + (a1.w + a3.w));
  size_t ob = (size_t)node * 32 + (q << 2);
  if (prev != nullptr) {
    uint2 pv = *reinterpret_cast<const uint2*>(&prev[ob]);
    float4 p = up4(pv);
    r.x = fmaf(beta, p.x, r.x);
    r.y = fmaf(beta, p.y, r.y);
    r.z = fmaf(beta, p.z, r.z);
    r.w = fmaf(beta, p.w, r.w);
  }
  __half2 h0 = __floats2half2_rn(r.x, r.y);
  __half2 h1 = __floats2half2_rn(r.z, r.w);
  uint2 o;
  o.x = *reinterpret_cast<unsigned*>(&h0);
  o.y = *reinterpret_cast<unsigned*>(&h1);
  *reinterpret_cast<uint2*>(&y16[ob]) = o;
}

// ---- weight prep: B fragments for 16x16x16 f16 MFMA + fused bias ----------
__global__ __launch_bounds__(TPB) void k_build_wt(
    const float* __restrict__ Wx, const float* __restrict__ bx,
    const float* __restrict__ bh, const float* __restrict__ bb,
    __half* __restrict__ Bf, float* __restrict__ be) {
  int idx = blockIdx.x * TPB + threadIdx.x;
  if (idx < 15360) {
    int t = idx / 2560, r1 = idx % 2560;
    int s = r1 / 256, r2 = r1 % 256;
    int l = r2 / 4, j = r2 % 4;
    int k = s * 16 + (l >> 4) * 4 + j;
    int c = t * 16 + (l & 15);
    int g3 = c >> 5, h = c & 31;
    int g = (g3 == 0) ? 0 : (g3 == 1 ? 2 : 3);
    int kk = k >> 5, i = k & 31;
    Bf[idx] = __float2half(Wx[((g * 5 + kk) * 32 + i) * 32 + h]);
  }
  if (idx < 96) {
    int g3 = idx >> 5, h = idx & 31;
    int g = (g3 == 0) ? 0 : (g3 == 1 ? 2 : 3);
    be[idx] = bx[g * 32 + h] + bh[g * 32 + h] + bb[g * 32 + h];
  }
}

// ---- head collapse: w_eff = hw1@hw2@hw3@hw4, b_eff similarly --------------
__global__ void k_head_setup(
    const float* __restrict__ hw1, const float* __restrict__ hb1,
    const float* __restrict__ hw2, const float* __restrict__ hb2,
    const float* __restrict__ hw3, const float* __restrict__ hb3,
    const float* __restrict__ hw4, const float* __restrict__ hb4,
    float* __restrict__ weff) {
  int a = threadIdx.x;
  if (a < 32) {
    float w12[8];
    for (int c = 0; c < 8; ++c) {
      float s = 0.f;
      for (int b = 0; b < 16; ++b) s += hw1[a * 16 + b] * hw2[b * 8 + c];
      w12[c] = s;
    }
    float w123[4];
    for (int d = 0; d < 4; ++d) {
      float s = 0.f;
      for (int c = 0; c < 8; ++c) s += w12[c] * hw3[c * 4 + d];
      w123[d] = s;
    }
    float s = 0.f;
    for (int d = 0; d < 4; ++d) s += w123[d] * hw4[d];
    weff[a] = s;
  }
  if (a == 32) {
    float t2[8];
    for (int c = 0; c < 8; ++c) {
      float s = hb2[c];
      for (int b = 0; b < 16; ++b) s += hb1[b] * hw2[b * 8 + c];
      t2[c] = s;
    }
    float t3[4];
    for (int d = 0; d < 4; ++d) {
      float s = hb3[d];
      for (int c = 0; c < 8; ++c) s += t2[c] * hw3[c * 4 + d];
      t3[d] = s;
    }
    float s = hb4[0];
    for (int d = 0; d < 4; ++d) s += t3[d] * hw4[d];
    weff[32] = s;
  }
}

// ---- fused gates on matrix cores ------------------------------------------
// 256 thr = 4 waves; wave w: nodes [base+16w, +16). 10 ksteps x 6 n-tiles
// of v_mfma_f32_16x16x16_f16. Epilogue: gate math; layer1 -> h16 only,
// layer2 -> fused head scalar.
__global__ __launch_bounds__(256) void k_gates_mfma(
    const __half* __restrict__ tab0, const __half* __restrict__ tab1,
    const __half* __restrict__ tab2, const __half* __restrict__ tab3,
    const __half* __restrict__ tab4, const __half* __restrict__ Bf,
    const float* __restrict__ be, const float* __restrict__ wc2,
    __half* __restrict__ H16, const float* __restrict__ weff,
    float* __restrict__ outHead, int n) {
  __shared__ float Hl[64][33];
  __shared__ float P[64][17];
  int tid = threadIdx.x;
  int w = tid >> 6, l = tid & 63;
  int lo = l & 15, hi = l >> 4;
  int base16 = blockIdx.x * 64 + w * 16;
  int anode = base16 + lo;
  if (anode >= n) anode = n - 1;  // clamp loads; stores guarded below

  f32x4 acc[6];
#pragma unroll
  for (int t = 0; t < 6; ++t) acc[t] = (f32x4){0.f, 0.f, 0.f, 0.f};

#pragma unroll
  for (int s = 0; s < 10; ++s) {
    const __half* tp = (s < 2) ? tab0 : (s < 4) ? tab1 : (s < 6) ? tab2
                       : (s < 8) ? tab3 : tab4;
    f16x4 a = *reinterpret_cast<const f16x4*>(tp + (size_t)anode * 32 +
                                              (s & 1) * 16 + hi * 4);
#pragma unroll
    for (int t = 0; t < 6; ++t) {
      f16x4 b =
          *reinterpret_cast<const f16x4*>(Bf + ((t * 10 + s) * 64 + l) * 4);
      acc[t] = __builtin_amdgcn_mfma_f32_16x16x16f16(a, b, acc[t], 0, 0, 0);
    }
  }

#pragma unroll
  for (int r = 0; r < 4; ++r) {
    int nl = w * 16 + hi * 4 + r;  // local node of D row
    float part = 0.f;
#pragma unroll
    for (int u = 0; u < 2; ++u) {
      int h = u * 16 + lo;
      float pi = acc[u][r] + be[h];
      float pc = acc[2 + u][r] + be[32 + h];
      float po = acc[4 + u][r] + be[64 + h];
      float I = 1.f / (1.f + expf(-pi));
      float Cn = I * tanhf(pc);
      float O = 1.f / (1.f + expf(-(po + wc2[h] * Cn)));
      float hv = fmaxf(O * tanhf(Cn), 0.f);
      if (outHead != nullptr)
        part = fmaf(hv, weff[h], part);
      else
        Hl[nl][h] = hv;
    }
    if (outHead != nullptr) P[nl][lo] = part;
  }
  __syncthreads();

  if (outHead != nullptr) {
    if (tid < 64) {
      int gn = blockIdx.x * 64 + tid;
      if (gn < n) {
        float s = weff[32];
#pragma unroll
        for (int c = 0; c < 16; ++c) s += P[tid][c];
        outHead[gn] = s;
      }
    }
  } else {
    for (int q = tid; q < 1024; q += 256) {  // fp16 H for next gather
      int node = q >> 4, fp = q & 15;
      int gn = blockIdx.x * 64 + node;
      if (gn < n) {
        __half2 hp = __floats2half2_rn(Hl[node][fp * 2], Hl[node][fp * 2 + 1]);
        *reinterpret_cast<__half2*>(&H16[(size_t)gn * 32 + fp * 2]) = hp;
      }
    }
  }
}

extern "C" void kernel_launch(void* const* d_in, const int* in_sizes, int n_in,
                              void* d_out, int out_size, void* d_ws,
                              size_t ws_size, hipStream_t stream) {
  const float* x = (const float*)d_in[0];
  const int* ei = (const int*)d_in[1];
  const float* ew = (const float*)d_in[2];
  const float* l1_Wx = (const float*)d_in[3];
  const float* l1_bx = (const float*)d_in[4];
  const float* l1_bh = (const float*)d_in[6];
  const float* l1_wc = (const float*)d_in[7];
  const float* l1_b = (const float*)d_in[8];
  const float* l2_Wx = (const float*)d_in[9];
  const float* l2_bx = (const float*)d_in[10];
  const float* l2_bh = (const float*)d_in[12];
  const float* l2_wc = (const float*)d_in[13];
  const float* l2_b = (const float*)d_in[14];
  const float* hw1 = (const float*)d_in[15];
  const float* hb1 = (const float*)d_in[16];
  const float* hw2 = (const float*)d_in[17];
  const float* hb2 = (const float*)d_in[18];
  const float* hw3 = (const float*)d_in[19];
  const float* hb3 = (const float*)d_in[20];
  const float* hw4 = (const float*)d_in[21];
  const float* hb4 = (const float*)d_in[22];

  const int N = in_sizes[0] / 32;
  const int E = in_sizes[1] / 2;
  const size_t EPAD = (size_t)E + 16 * (size_t)N;  // padded CSR capacity
  const size_t TBL = (size_t)(N + 64) * 32 * 2;    // fp16 table (+pad rows)

  // workspace carve-out (256B aligned)
  char* w = (char*)d_ws;
  auto alloc = [&](size_t bytes) -> void* {
    void* p = (void*)w;
    w += (bytes + 255) & ~(size_t)255;
    return p;
  };
  float* dinv = (float*)alloc((size_t)N * 4);
  int* cnt = (int*)alloc((size_t)N * 4);
  int* rp = (int*)alloc((size_t)(N + 1) * 4);
  int* excl = (int*)alloc((size_t)N * 4);
  int* bsum = (int*)alloc(256 * 4);
  int* dcnt = (int*)alloc(512 * 4);  // contiguous with scnt: single memset
  int* scnt = (int*)alloc(512 * 4);
  uint2* epk = (uint2*)alloc(EPAD * 8);
  uint2* arD = (uint2*)alloc((size_t)NB * CAP * 8);
  unsigned* arS = (unsigned*)alloc((size_t)NB * CAP * 4);
  __half* Bf1 = (__half*)alloc(15360 * 2);
  float* be1 = (float*)alloc(96 * 4);
  __half* Bf2 = (__half*)alloc(15360 * 2);
  float* be2 = (float*)alloc(96 * 4);
  float* weff = (float*)alloc(40 * 4);
  __half* x16 = (__half*)alloc(TBL);
  __half* h16 = (__half*)alloc(TBL);
  __half* t16a = (__half*)alloc(TBL);
  __half* t16b = (__half*)alloc(TBL);
  __half* t16c = (__half*)alloc(TBL);
  __half* t16d = (__half*)alloc(TBL);

  const int gBK = (E + EPB - 1) / EPB;
  const int gN = (N + TPB - 1) / TPB;
  const int gP = (N + 31) / 32;
  const int gG = (N + 63) / 64;
  const int gH = (N * 8 + TPB - 1) / TPB;

  hipMemsetAsync(dcnt, 0, 1024 * 4, stream);  // dcnt + scnt
  hipMemsetAsync(epk, 0, EPAD * 8, stream);   // zero pads

  // CSR build (LDS-staged radix scatter)
  k_bucket<<<gBK, 512, 0, stream>>>(ei, ew, dcnt, scnt, arD, arS, E);
  k_degcnt<<<NB, TPB, 0, stream>>>(arS, scnt, arD, dcnt, dinv, cnt, N);
  k_scan1<<<gN, TPB, 0, stream>>>(cnt, excl, bsum, N);
  k_scan2<<<1, TPB, 0, stream>>>(bsum, gN);
  k_scan3<<<gN, TPB, 0, stream>>>(excl, bsum, cnt, rp, N);
  k_csr<<<NB, TPB, 0, stream>>>(arD, dcnt, rp, dinv, epk, N);

  // weight prep + fp16 x table
  k_build_wt<<<60, TPB, 0, stream>>>(l1_Wx, l1_bx, l1_bh, l1_b, Bf1, be1);
  k_build_wt<<<60, TPB, 0, stream>>>(l2_Wx, l2_bx, l2_bh, l2_b, Bf2, be2);
  k_head_setup<<<1, 64, 0, stream>>>(hw1, hb1, hw2, hb2, hw3, hb3, hw4, hb4,
                                     weff);
  k_tohalf<<<gH, TPB, 0, stream>>>(x, x16, N * 8);

  // layer 1 (T0 = x16); fp16-only recurrence
  k_prop16<<<gP, TPB, 0, stream>>>(x16, rp, epk, nullptr, 1.f, 0.f, t16a, N);
  k_prop16<<<gP, TPB, 0, stream>>>(t16a, rp, epk, x16, 2.f, -1.f, t16b, N);
  k_prop16<<<gP, TPB, 0, stream>>>(t16b, rp, epk, t16a, 2.f, -1.f, t16c, N);
  k_prop16<<<gP, TPB, 0, stream>>>(t16c, rp, epk, t16b, 2.f, -1.f, t16d, N);
  k_gates_mfma<<<gG, 256, 0, stream>>>(x16, t16a, t16b, t16c, t16d, Bf1, be1,
                                       l1_wc + 64, h16, nullptr, nullptr, N);

  // layer 2 (T0 = h16)
  k_prop16<<<gP, TPB, 0, stream>>>(h16, rp, epk, nullptr, 1.f, 0.f, t16a, N);
  k_prop16<<<gP, TPB, 0, stream>>>(t16a, rp, epk, h16, 2.f, -1.f, t16b, N);
  k_prop16<<<gP, TPB, 0, stream>>>(t16b, rp, epk, t16a, 2.f, -1.f, t16c, N);
  k_prop16<<<gP, TPB, 0, stream>>>(t16c, rp, epk, t16b, 2.f, -1.f, t16d, N);
  k_gates_mfma<<<gG, 256, 0, stream>>>(h16, t16a, t16b, t16c, t16d, Bf2, be2,
                                       l2_wc + 64, nullptr, weff,
                                       (float*)d_out, N);
}